// Round 10
// baseline (955.652 us; speedup 1.0000x reference)
//
#include <hip/hip_runtime.h>
#include <cstddef>

// Problem constants (fixed by setup_inputs)
#define NN   102400   // nodes
#define D    128      // feature dim
#define D2   256      // hidden dim
#define NE   819200   // edges
#define NL   5        // layers
#define NSG  1024     // total subgraphs
#define SGN  100      // nodes per subgraph

typedef __attribute__((ext_vector_type(8))) short short8;   // 8 bf16 (4 VGPRs)
typedef __attribute__((ext_vector_type(4))) float f32x4;

__device__ __forceinline__ float bf2f(unsigned short u) {
  union { unsigned int i; float f; } c; c.i = ((unsigned int)u) << 16; return c.f;
}
__device__ __forceinline__ unsigned short f2bf(float f) {
  union { float f; unsigned int i; } c; c.f = f;
  unsigned int x = c.i;
  return (unsigned short)((x + 0x7fffu + ((x >> 16) & 1u)) >> 16);  // RNE
}

// ---------------- CSR build (by dst), rank-based (one atomic pass) ----------------
__global__ void k_count(const int* __restrict__ dst, int* __restrict__ deg,
                        int* __restrict__ rank) {
  int e = blockIdx.x * blockDim.x + threadIdx.x;
  if (e < NE) rank[e] = atomicAdd(&deg[dst[e]], 1);
}

__global__ void k_scan_local(const int* __restrict__ deg, int* __restrict__ incl,
                             int* __restrict__ part) {
  __shared__ int s[1024];
  int i = blockIdx.x * 1024 + threadIdx.x;
  s[threadIdx.x] = deg[i];
  __syncthreads();
  for (int off = 1; off < 1024; off <<= 1) {
    int t = (threadIdx.x >= off) ? s[threadIdx.x - off] : 0;
    __syncthreads();
    s[threadIdx.x] += t;
    __syncthreads();
  }
  incl[i] = s[threadIdx.x];
  if (threadIdx.x == 1023) part[blockIdx.x] = s[1023];
}

__global__ void k_scan_part(int* part, int nb) {
  if (threadIdx.x == 0 && blockIdx.x == 0) {
    int acc = 0;
    for (int i = 0; i < nb; ++i) { int t = part[i]; part[i] = acc; acc += t; }
  }
}

__global__ void k_scan_fin(const int* __restrict__ incl, const int* __restrict__ part,
                           int* __restrict__ rowptr) {
  int i = blockIdx.x * blockDim.x + threadIdx.x;
  if (i < NN) rowptr[i + 1] = incl[i] + part[i >> 10];
  if (i == 0) rowptr[0] = 0;
}

__global__ void k_fill(const int* __restrict__ src, const int* __restrict__ dst,
                       const int* __restrict__ rowptr, const int* __restrict__ rank,
                       int* __restrict__ csrsrc) {
  int e = blockIdx.x * blockDim.x + threadIdx.x;
  if (e < NE) csrsrc[rowptr[dst[e]] + rank[e]] = src[e];   // no atomics
}

// ---------------- prep: x fp32 -> bf16 ----------------
__global__ void k_cvt_x(const float* __restrict__ x, unsigned short* __restrict__ xb) {
  int i = blockIdx.x * 256 + threadIdx.x;     // one short8 per thread
  const float* p = x + (size_t)i * 8;
  float4 a = *(const float4*)p;
  float4 b = *(const float4*)(p + 4);
  short8 o;
  o[0] = (short)f2bf(a.x); o[1] = (short)f2bf(a.y);
  o[2] = (short)f2bf(a.z); o[3] = (short)f2bf(a.w);
  o[4] = (short)f2bf(b.x); o[5] = (short)f2bf(b.y);
  o[6] = (short)f2bf(b.z); o[7] = (short)f2bf(b.w);
  *(short8*)(xb + (size_t)i * 8) = o;
}

// ---------------- prep: weights fp32 -> bf16, transposed [n][k] ----------------
__global__ void k_prep_w(const float* __restrict__ W1, const float* __restrict__ W2,
                         unsigned short* __restrict__ W1t, unsigned short* __restrict__ W2t) {
  int i = blockIdx.x * 256 + threadIdx.x;     // 0 .. L*D*D2-1
  int l = i >> 15;                             // / (128*256)
  int rem = i & 32767;
  int n1 = rem >> 7, k1 = rem & 127;           // W1t[l][n1][k1] = W1[l][k1][n1]
  W1t[i] = f2bf(W1[(size_t)l * D * D2 + (size_t)k1 * D2 + n1]);
  int n2 = rem >> 8, k2 = rem & 255;           // W2t[l][n2][k2] = W2[l][k2][n2]
  W2t[i] = f2bf(W2[(size_t)l * D2 * D + (size_t)k2 * D + n2]);
}

// ---------------- fused GIN layer: agg -> GEMM1 -> ReLU -> GEMM2 ----------------
// r9: block = 64 rows, 4 waves x 16 rows each -> grid 1600 blocks (was 800).
// r8 post-mortem: occupancy was GRID-limited (800 blk x 4 waves = 39% cap,
// measured 15.7%) -> latency-bound gather had ~1 wave/SIMD to hide under.
// Halving rows/wave doubles blocks; persistent regs drop (azf 16, acc2 32).
// n-CHUNKED chaining kept: z1 in 4 chunks of 64 cols; GEMM1 chunk -> ReLU ->
// 2KB wave-private LDS -> GEMM2 partial-K (acc2 += across chunks).
// VGPR NOTE (r7 lesson): live regs ~100 < 128 cap of (256,4); if WRITE_SIZE
// rises above 25.6MB/layer the allocator spilled -> relax to (256,2).
// Fragment layout (m89/m91): A lane: row=l&15, k=(l>>4)*8+j; B lane: col=l&15;
// C/D: col=l&15, row=(l>>4)*4+r. LDS [16][64] bf16, byte ^= (row&7)<<4.
template<bool RELU_OUT>
__global__ __launch_bounds__(256, 4) void k_layer(
    const unsigned short* __restrict__ hin, const int* __restrict__ rowptr,
    const int* __restrict__ csrsrc,
    const unsigned short* __restrict__ W1t,   // [256][128] bf16
    const float* __restrict__ b1,             // [256]
    const unsigned short* __restrict__ W2t,   // [128][256] bf16
    const float* __restrict__ b2,             // [128]
    const float* __restrict__ eps, int layer,
    unsigned short* __restrict__ hout) {
  __shared__ char lds[4 * 2048];
  int w = threadIdx.x >> 6, lane = threadIdx.x & 63;
  int l15 = lane & 15, q = lane >> 4;
  char* my = lds + w * 2048;                  // wave-private z1 chunk [16][64] bf16
  float ep1 = 1.0f + eps[layer];
  int rowA = blockIdx.x * 64 + w * 16;        // wave rows [rowA, rowA+16)

  // ---- phase 1: gather agg for 1 row/lane straight into A-fragments
  short8 azf[4];
  {
    int r = rowA + l15;
    const unsigned short* hr = hin + (size_t)r * D + q * 8;
    float acc[4][8];
#pragma unroll
    for (int kf = 0; kf < 4; ++kf) {
      short8 v = *(const short8*)(hr + kf * 32);
#pragma unroll
      for (int j = 0; j < 8; ++j) acc[kf][j] = ep1 * bf2f((unsigned short)v[j]);
    }
    int e = rowptr[r], e1 = rowptr[r + 1];
    for (; e + 1 < e1; e += 2) {               // 2 edges in flight (8x16B loads)
      int u0 = csrsrc[e], u1 = csrsrc[e + 1];
      const unsigned short* hu0 = hin + (size_t)u0 * D + q * 8;
      const unsigned short* hu1 = hin + (size_t)u1 * D + q * 8;
#pragma unroll
      for (int kf = 0; kf < 4; ++kf) {
        short8 v0 = *(const short8*)(hu0 + kf * 32);
        short8 v1 = *(const short8*)(hu1 + kf * 32);
#pragma unroll
        for (int j = 0; j < 8; ++j)
          acc[kf][j] += bf2f((unsigned short)v0[j]) + bf2f((unsigned short)v1[j]);
      }
    }
    if (e < e1) {
      int u0 = csrsrc[e];
      const unsigned short* hu0 = hin + (size_t)u0 * D + q * 8;
#pragma unroll
      for (int kf = 0; kf < 4; ++kf) {
        short8 v0 = *(const short8*)(hu0 + kf * 32);
#pragma unroll
        for (int j = 0; j < 8; ++j) acc[kf][j] += bf2f((unsigned short)v0[j]);
      }
    }
#pragma unroll
    for (int kf = 0; kf < 4; ++kf) {
      short8 o;
#pragma unroll
      for (int j = 0; j < 8; ++j) o[j] = (short)f2bf(acc[kf][j]);
      azf[kf] = o;
    }
  }

  // ---- phases 2+3 chained per 64-col chunk of z1
  f32x4 acc2[8] = {};
#pragma unroll
  for (int nc = 0; nc < 4; ++nc) {
    // GEMM1 chunk: z1[:, nc*64 .. nc*64+63] = relu(az @ W1 + b1)
    f32x4 acc1[4] = {};
#pragma unroll
    for (int kf = 0; kf < 4; ++kf) {
#pragma unroll
      for (int n = 0; n < 4; ++n) {
        int col = nc * 64 + n * 16 + l15;
        short8 bf = *(const short8*)(W1t + (size_t)col * D + kf * 32 + q * 8);
        acc1[n] = __builtin_amdgcn_mfma_f32_16x16x32_bf16(azf[kf], bf, acc1[n], 0, 0, 0);
      }
    }
#pragma unroll
    for (int n = 0; n < 4; ++n) {
      int cc = n * 16 + l15;                   // col within chunk (0..63)
      float bb = b1[nc * 64 + cc];
#pragma unroll
      for (int r = 0; r < 4; ++r) {
        int rs = q * 4 + r;                    // row within 16-row slice
        float v = fmaxf(acc1[n][r] + bb, 0.f);
        int byte = (rs << 7) + cc * 2;
        byte ^= (rs & 7) << 4;
        *(unsigned short*)(my + byte) = f2bf(v);
      }
    }
    // GEMM2 partial-K: acc2 += z1chunk @ W2[nc*64 .. nc*64+63, :]
#pragma unroll
    for (int kk = 0; kk < 2; ++kk) {           // two 32-wide K-slices in chunk
      short8 af;
      {
        int rs = l15;
        int byte = (rs << 7) + kk * 64 + q * 16;
        byte ^= (rs & 7) << 4;
        af = *(const short8*)(my + byte);
      }
#pragma unroll
      for (int n2 = 0; n2 < 8; ++n2) {
        short8 bf = *(const short8*)(W2t + (size_t)(n2 * 16 + l15) * D2 +
                                     nc * 64 + kk * 32 + q * 8);
        acc2[n2] = __builtin_amdgcn_mfma_f32_16x16x32_bf16(af, bf, acc2[n2], 0, 0, 0);
      }
    }
  }

  // ---- epilogue
#pragma unroll
  for (int n2 = 0; n2 < 8; ++n2) {
    int col = n2 * 16 + l15;
    float bb = b2[col];
#pragma unroll
    for (int r = 0; r < 4; ++r) {
      int row = rowA + q * 4 + r;
      float v = acc2[n2][r] + bb;
      if (RELU_OUT) v = fmaxf(v, 0.f);
      hout[(size_t)row * D + col] = f2bf(v);
    }
  }
}

// ---------------- subgraph mean pool (bf16 in, fp32 out) ----------------
__global__ __launch_bounds__(256) void k_pool(const unsigned short* __restrict__ h,
                                              float* __restrict__ out) {
  __shared__ float red[16][132];
  int g = threadIdx.x >> 4;
  int ln = threadIdx.x & 15;
  int sg = blockIdx.x;
  float acc[8] = {0.f, 0.f, 0.f, 0.f, 0.f, 0.f, 0.f, 0.f};
  for (int r = g; r < SGN; r += 16) {
    short8 v = *(const short8*)(h + ((size_t)sg * SGN + r) * D + (size_t)ln * 8);
#pragma unroll
    for (int j = 0; j < 8; ++j) acc[j] += bf2f((unsigned short)v[j]);
  }
#pragma unroll
  for (int j = 0; j < 8; ++j) red[g][ln * 8 + j] = acc[j];
  __syncthreads();
  if (threadIdx.x < 128) {
    float s = 0.f;
#pragma unroll
    for (int i = 0; i < 16; ++i) s += red[i][threadIdx.x];
    out[(size_t)sg * D + threadIdx.x] = s * 0.01f;
  }
}

extern "C" void kernel_launch(void* const* d_in, const int* in_sizes, int n_in,
                              void* d_out, int out_size, void* d_ws, size_t ws_size,
                              hipStream_t stream) {
  const float* x   = (const float*)d_in[0];
  const int*   ei  = (const int*)d_in[1];
  const float* W1  = (const float*)d_in[5];
  const float* b1  = (const float*)d_in[6];
  const float* W2  = (const float*)d_in[7];
  const float* b2  = (const float*)d_in[8];
  const float* eps = (const float*)d_in[9];
  const int* src = ei;        // edge_index[0]
  const int* dst = ei + NE;   // edge_index[1]

  char* p = (char*)d_ws;
  unsigned short* xb  = (unsigned short*)p; p += (size_t)NN * D * 2;
  unsigned short* hb  = (unsigned short*)p; p += (size_t)NN * D * 2;
  unsigned short* zb  = (unsigned short*)p; p += (size_t)NN * D * 2;
  unsigned short* W1t = (unsigned short*)p; p += (size_t)NL * D * D2 * 2;
  unsigned short* W2t = (unsigned short*)p; p += (size_t)NL * D * D2 * 2;
  int* deg    = (int*)p;   p += (size_t)NN * 4;
  int* incl   = (int*)p;   p += (size_t)NN * 4;
  int* part   = (int*)p;   p += 128 * 4;
  int* rowptr = (int*)p;   p += (size_t)(NN + 1) * 4;
  int* rank   = (int*)p;   p += (size_t)NE * 4;
  int* csrsrc = (int*)p;   p += (size_t)NE * 4;

  hipMemsetAsync(deg, 0, (size_t)NN * 4, stream);
  k_count<<<NE / 256, 256, 0, stream>>>(dst, deg, rank);
  k_scan_local<<<NN / 1024, 1024, 0, stream>>>(deg, incl, part);
  k_scan_part<<<1, 64, 0, stream>>>(part, NN / 1024);
  k_scan_fin<<<NN / 256, 256, 0, stream>>>(incl, part, rowptr);
  k_fill<<<NE / 256, 256, 0, stream>>>(src, dst, rowptr, rank, csrsrc);

  k_cvt_x<<<NN * D / 8 / 256, 256, 0, stream>>>(x, xb);
  k_prep_w<<<NL * D * D2 / 256, 256, 0, stream>>>(W1, W2, W1t, W2t);

  const unsigned short* cur = xb;
  unsigned short* nxt = hb;
  for (int l = 0; l < NL; ++l) {
    const unsigned short* w1l = W1t + (size_t)l * D * D2;
    const unsigned short* w2l = W2t + (size_t)l * D * D2;
    const float* b1l = b1 + (size_t)l * D2;
    const float* b2l = b2 + (size_t)l * D;
    if (l < NL - 1)
      k_layer<true><<<NN / 64, 256, 0, stream>>>(cur, rowptr, csrsrc, w1l, b1l,
                                                 w2l, b2l, eps, l, nxt);
    else
      k_layer<false><<<NN / 64, 256, 0, stream>>>(cur, rowptr, csrsrc, w1l, b1l,
                                                  w2l, b2l, eps, l, nxt);
    cur = nxt;
    nxt = (cur == hb) ? zb : hb;
  }
  k_pool<<<NSG, 256, 0, stream>>>((const unsigned short*)cur, (float*)d_out);
}

// Round 11
// 702.466 us; speedup vs baseline: 1.3604x; 1.3604x over previous
//
#include <hip/hip_runtime.h>
#include <cstddef>

// Problem constants (fixed by setup_inputs)
#define NN   102400   // nodes
#define D    128      // feature dim
#define D2   256      // hidden dim
#define NE   819200   // edges
#define NL   5        // layers
#define NSG  1024     // total subgraphs
#define SGN  100      // nodes per subgraph

typedef __attribute__((ext_vector_type(8))) short short8;   // 8 bf16 (4 VGPRs)
typedef __attribute__((ext_vector_type(4))) float f32x4;

__device__ __forceinline__ float bf2f(unsigned short u) {
  union { unsigned int i; float f; } c; c.i = ((unsigned int)u) << 16; return c.f;
}
__device__ __forceinline__ unsigned short f2bf(float f) {
  union { float f; unsigned int i; } c; c.f = f;
  unsigned int x = c.i;
  return (unsigned short)((x + 0x7fffu + ((x >> 16) & 1u)) >> 16);  // RNE
}

// ---------------- CSR build (by dst), rank-based (one atomic pass) ----------------
__global__ void k_count(const int* __restrict__ dst, int* __restrict__ deg,
                        int* __restrict__ rank) {
  int e = blockIdx.x * blockDim.x + threadIdx.x;
  if (e < NE) rank[e] = atomicAdd(&deg[dst[e]], 1);
}

__global__ void k_scan_local(const int* __restrict__ deg, int* __restrict__ incl,
                             int* __restrict__ part) {
  __shared__ int s[1024];
  int i = blockIdx.x * 1024 + threadIdx.x;
  s[threadIdx.x] = deg[i];
  __syncthreads();
  for (int off = 1; off < 1024; off <<= 1) {
    int t = (threadIdx.x >= off) ? s[threadIdx.x - off] : 0;
    __syncthreads();
    s[threadIdx.x] += t;
    __syncthreads();
  }
  incl[i] = s[threadIdx.x];
  if (threadIdx.x == 1023) part[blockIdx.x] = s[1023];
}

__global__ void k_scan_part(int* part, int nb) {
  if (threadIdx.x == 0 && blockIdx.x == 0) {
    int acc = 0;
    for (int i = 0; i < nb; ++i) { int t = part[i]; part[i] = acc; acc += t; }
  }
}

__global__ void k_scan_fin(const int* __restrict__ incl, const int* __restrict__ part,
                           int* __restrict__ rowptr) {
  int i = blockIdx.x * blockDim.x + threadIdx.x;
  if (i < NN) rowptr[i + 1] = incl[i] + part[i >> 10];
  if (i == 0) rowptr[0] = 0;
}

__global__ void k_fill(const int* __restrict__ src, const int* __restrict__ dst,
                       const int* __restrict__ rowptr, const int* __restrict__ rank,
                       int* __restrict__ csrsrc) {
  int e = blockIdx.x * blockDim.x + threadIdx.x;
  if (e < NE) csrsrc[rowptr[dst[e]] + rank[e]] = src[e];   // no atomics
}

// ---------------- prep: x fp32 -> bf16 ----------------
__global__ void k_cvt_x(const float* __restrict__ x, unsigned short* __restrict__ xb) {
  int i = blockIdx.x * 256 + threadIdx.x;     // one short8 per thread
  const float* p = x + (size_t)i * 8;
  float4 a = *(const float4*)p;
  float4 b = *(const float4*)(p + 4);
  short8 o;
  o[0] = (short)f2bf(a.x); o[1] = (short)f2bf(a.y);
  o[2] = (short)f2bf(a.z); o[3] = (short)f2bf(a.w);
  o[4] = (short)f2bf(b.x); o[5] = (short)f2bf(b.y);
  o[6] = (short)f2bf(b.z); o[7] = (short)f2bf(b.w);
  *(short8*)(xb + (size_t)i * 8) = o;
}

// ---------------- prep: weights fp32 -> bf16, transposed [n][k] ----------------
__global__ void k_prep_w(const float* __restrict__ W1, const float* __restrict__ W2,
                         unsigned short* __restrict__ W1t, unsigned short* __restrict__ W2t) {
  int i = blockIdx.x * 256 + threadIdx.x;     // 0 .. L*D*D2-1
  int l = i >> 15;                             // / (128*256)
  int rem = i & 32767;
  int n1 = rem >> 7, k1 = rem & 127;           // W1t[l][n1][k1] = W1[l][k1][n1]
  W1t[i] = f2bf(W1[(size_t)l * D * D2 + (size_t)k1 * D2 + n1]);
  int n2 = rem >> 8, k2 = rem & 255;           // W2t[l][n2][k2] = W2[l][k2][n2]
  W2t[i] = f2bf(W2[(size_t)l * D2 * D + (size_t)k2 * D + n2]);
}

// ---------------- GIN aggregation (standalone, latency-tuned) ----------------
// r10 post-mortem: fusing gather with GEMMs couples incompatible regimes
// (gather wants max waves + low regs; GEMMs want big tiles + many regs).
// Split. 16 lanes/node (16B=8 bf16 per lane), 16 nodes per 256-thr block,
// edge loop unrolled x4 -> 16 outstanding 16B loads/lane. VGPR ~40 -> high
// occupancy. h is L2/L3-resident (26MB); this kernel is pure latency-hiding.
__global__ __launch_bounds__(256) void k_agg(const unsigned short* __restrict__ h,
                                             const int* __restrict__ rowptr,
                                             const int* __restrict__ csrsrc,
                                             const float* __restrict__ eps, int layer,
                                             unsigned short* __restrict__ z) {
  int g = threadIdx.x >> 4;
  int ln = threadIdx.x & 15;
  int v = blockIdx.x * 16 + g;
  float ep1 = 1.0f + eps[layer];
  const size_t off = (size_t)ln * 8;

  short8 hv = *(const short8*)(h + (size_t)v * D + off);
  float acc[8];
#pragma unroll
  for (int j = 0; j < 8; ++j) acc[j] = ep1 * bf2f((unsigned short)hv[j]);

  int e = rowptr[v], r1 = rowptr[v + 1];
  for (; e + 3 < r1; e += 4) {
    int u0 = csrsrc[e], u1 = csrsrc[e + 1], u2 = csrsrc[e + 2], u3 = csrsrc[e + 3];
    short8 a = *(const short8*)(h + (size_t)u0 * D + off);
    short8 b = *(const short8*)(h + (size_t)u1 * D + off);
    short8 c = *(const short8*)(h + (size_t)u2 * D + off);
    short8 d = *(const short8*)(h + (size_t)u3 * D + off);
#pragma unroll
    for (int j = 0; j < 8; ++j)
      acc[j] += (bf2f((unsigned short)a[j]) + bf2f((unsigned short)b[j])) +
                (bf2f((unsigned short)c[j]) + bf2f((unsigned short)d[j]));
  }
  for (; e < r1; ++e) {
    int u0 = csrsrc[e];
    short8 a = *(const short8*)(h + (size_t)u0 * D + off);
#pragma unroll
    for (int j = 0; j < 8; ++j) acc[j] += bf2f((unsigned short)a[j]);
  }

  short8 o;
#pragma unroll
  for (int j = 0; j < 8; ++j) o[j] = (short)f2bf(acc[j]);
  *(short8*)(z + (size_t)v * D + off) = o;
}

// ---------------- fused MLP: h_out = (relu?)(relu(z@W1+b1)@W2+b2) ----------------
// Dense, regular (no gather). Block = 128 rows, 4 waves x 32 rows; z1 chunked
// in 4x 64-col pieces through a 4KB wave-private LDS buffer (16KB/block);
// GEMM2 accumulates across chunks. No __syncthreads (wave-private LDS).
// VGPR ~150 live -> (256,2) cap 256, no spill (r7 rule: never cap below live).
// Spill tripwire: WRITE_SIZE must stay 25.6MB/dispatch (h-out only).
// Fragment layout (m89/m91): A lane: row=l&15, k=(l>>4)*8+j; B lane: col=l&15;
// C/D: col=l&15, row=(l>>4)*4+r. LDS [32][64] bf16, byte ^= (rs&7)<<4 swizzle.
template<bool RELU_OUT>
__global__ __launch_bounds__(256, 2) void k_mlp(
    const unsigned short* __restrict__ z,     // [NN][128] bf16 (agg output)
    const unsigned short* __restrict__ W1t,   // [256][128] bf16
    const float* __restrict__ b1,             // [256]
    const unsigned short* __restrict__ W2t,   // [128][256] bf16
    const float* __restrict__ b2,             // [128]
    unsigned short* __restrict__ hout) {
  __shared__ char lds[4 * 4096];
  int w = threadIdx.x >> 6, lane = threadIdx.x & 63;
  int l15 = lane & 15, q = lane >> 4;
  char* my = lds + w * 4096;                  // wave-private z1 chunk [32][64] bf16
  int rowA = blockIdx.x * 128 + w * 32;       // wave rows [rowA, rowA+32)

  // ---- A-fragments straight from z (coalesced 16B loads, L2-resident)
  short8 azf[2][4];
#pragma unroll
  for (int m = 0; m < 2; ++m)
#pragma unroll
    for (int kf = 0; kf < 4; ++kf)
      azf[m][kf] = *(const short8*)(z + (size_t)(rowA + m * 16 + l15) * D + kf * 32 + q * 8);

  // ---- GEMM1 chunk -> ReLU -> LDS -> GEMM2 partial-K, x4 chunks
  f32x4 acc2[2][8] = {};
#pragma unroll
  for (int nc = 0; nc < 4; ++nc) {
    f32x4 acc1[2][4] = {};
#pragma unroll
    for (int kf = 0; kf < 4; ++kf) {
#pragma unroll
      for (int n = 0; n < 4; ++n) {
        int col = nc * 64 + n * 16 + l15;
        short8 bf = *(const short8*)(W1t + (size_t)col * D + kf * 32 + q * 8);
        acc1[0][n] = __builtin_amdgcn_mfma_f32_16x16x32_bf16(azf[0][kf], bf, acc1[0][n], 0, 0, 0);
        acc1[1][n] = __builtin_amdgcn_mfma_f32_16x16x32_bf16(azf[1][kf], bf, acc1[1][n], 0, 0, 0);
      }
    }
#pragma unroll
    for (int m = 0; m < 2; ++m) {
#pragma unroll
      for (int n = 0; n < 4; ++n) {
        int cc = n * 16 + l15;                 // col within chunk (0..63)
        float bb = b1[nc * 64 + cc];
#pragma unroll
        for (int r = 0; r < 4; ++r) {
          int rs = m * 16 + q * 4 + r;         // row within 32-row slice
          float v = fmaxf(acc1[m][n][r] + bb, 0.f);
          int byte = (rs << 7) + cc * 2;
          byte ^= (rs & 7) << 4;
          *(unsigned short*)(my + byte) = f2bf(v);
        }
      }
    }
#pragma unroll
    for (int kk = 0; kk < 2; ++kk) {           // two 32-wide K-slices in chunk
      short8 af[2];
#pragma unroll
      for (int m = 0; m < 2; ++m) {
        int rs = m * 16 + l15;
        int byte = (rs << 7) + kk * 64 + q * 16;
        byte ^= (rs & 7) << 4;
        af[m] = *(const short8*)(my + byte);
      }
#pragma unroll
      for (int n2 = 0; n2 < 8; ++n2) {
        short8 bf = *(const short8*)(W2t + (size_t)(n2 * 16 + l15) * D2 +
                                     nc * 64 + kk * 32 + q * 8);
        acc2[0][n2] = __builtin_amdgcn_mfma_f32_16x16x32_bf16(af[0], bf, acc2[0][n2], 0, 0, 0);
        acc2[1][n2] = __builtin_amdgcn_mfma_f32_16x16x32_bf16(af[1], bf, acc2[1][n2], 0, 0, 0);
      }
    }
  }

  // ---- epilogue
#pragma unroll
  for (int m = 0; m < 2; ++m) {
#pragma unroll
    for (int n2 = 0; n2 < 8; ++n2) {
      int col = n2 * 16 + l15;
      float bb = b2[col];
#pragma unroll
      for (int r = 0; r < 4; ++r) {
        int row = rowA + m * 16 + q * 4 + r;
        float v = acc2[m][n2][r] + bb;
        if (RELU_OUT) v = fmaxf(v, 0.f);
        hout[(size_t)row * D + col] = f2bf(v);
      }
    }
  }
}

// ---------------- subgraph mean pool (bf16 in, fp32 out) ----------------
__global__ __launch_bounds__(256) void k_pool(const unsigned short* __restrict__ h,
                                              float* __restrict__ out) {
  __shared__ float red[16][132];
  int g = threadIdx.x >> 4;
  int ln = threadIdx.x & 15;
  int sg = blockIdx.x;
  float acc[8] = {0.f, 0.f, 0.f, 0.f, 0.f, 0.f, 0.f, 0.f};
  for (int r = g; r < SGN; r += 16) {
    short8 v = *(const short8*)(h + ((size_t)sg * SGN + r) * D + (size_t)ln * 8);
#pragma unroll
    for (int j = 0; j < 8; ++j) acc[j] += bf2f((unsigned short)v[j]);
  }
#pragma unroll
  for (int j = 0; j < 8; ++j) red[g][ln * 8 + j] = acc[j];
  __syncthreads();
  if (threadIdx.x < 128) {
    float s = 0.f;
#pragma unroll
    for (int i = 0; i < 16; ++i) s += red[i][threadIdx.x];
    out[(size_t)sg * D + threadIdx.x] = s * 0.01f;
  }
}

extern "C" void kernel_launch(void* const* d_in, const int* in_sizes, int n_in,
                              void* d_out, int out_size, void* d_ws, size_t ws_size,
                              hipStream_t stream) {
  const float* x   = (const float*)d_in[0];
  const int*   ei  = (const int*)d_in[1];
  const float* W1  = (const float*)d_in[5];
  const float* b1  = (const float*)d_in[6];
  const float* W2  = (const float*)d_in[7];
  const float* b2  = (const float*)d_in[8];
  const float* eps = (const float*)d_in[9];
  const int* src = ei;        // edge_index[0]
  const int* dst = ei + NE;   // edge_index[1]

  char* p = (char*)d_ws;
  unsigned short* xb  = (unsigned short*)p; p += (size_t)NN * D * 2;
  unsigned short* hb  = (unsigned short*)p; p += (size_t)NN * D * 2;
  unsigned short* zb  = (unsigned short*)p; p += (size_t)NN * D * 2;
  unsigned short* ga  = (unsigned short*)p; p += (size_t)NN * D * 2;  // agg out
  unsigned short* W1t = (unsigned short*)p; p += (size_t)NL * D * D2 * 2;
  unsigned short* W2t = (unsigned short*)p; p += (size_t)NL * D * D2 * 2;
  int* deg    = (int*)p;   p += (size_t)NN * 4;
  int* incl   = (int*)p;   p += (size_t)NN * 4;
  int* part   = (int*)p;   p += 128 * 4;
  int* rowptr = (int*)p;   p += (size_t)(NN + 1) * 4;
  int* rank   = (int*)p;   p += (size_t)NE * 4;
  int* csrsrc = (int*)p;   p += (size_t)NE * 4;

  hipMemsetAsync(deg, 0, (size_t)NN * 4, stream);
  k_count<<<NE / 256, 256, 0, stream>>>(dst, deg, rank);
  k_scan_local<<<NN / 1024, 1024, 0, stream>>>(deg, incl, part);
  k_scan_part<<<1, 64, 0, stream>>>(part, NN / 1024);
  k_scan_fin<<<NN / 256, 256, 0, stream>>>(incl, part, rowptr);
  k_fill<<<NE / 256, 256, 0, stream>>>(src, dst, rowptr, rank, csrsrc);

  k_cvt_x<<<NN * D / 8 / 256, 256, 0, stream>>>(x, xb);
  k_prep_w<<<NL * D * D2 / 256, 256, 0, stream>>>(W1, W2, W1t, W2t);

  const unsigned short* cur = xb;
  unsigned short* nxt = hb;
  for (int l = 0; l < NL; ++l) {
    const unsigned short* w1l = W1t + (size_t)l * D * D2;
    const unsigned short* w2l = W2t + (size_t)l * D * D2;
    const float* b1l = b1 + (size_t)l * D2;
    const float* b2l = b2 + (size_t)l * D;
    k_agg<<<NN / 16, 256, 0, stream>>>(cur, rowptr, csrsrc, eps, l, ga);
    if (l < NL - 1)
      k_mlp<true><<<NN / 128, 256, 0, stream>>>(ga, w1l, b1l, w2l, b2l, nxt);
    else
      k_mlp<false><<<NN / 128, 256, 0, stream>>>(ga, w1l, b1l, w2l, b2l, nxt);
    cur = nxt;
    nxt = (cur == hb) ? zb : hb;
  }
  k_pool<<<NSG, 256, 0, stream>>>((const unsigned short*)cur, (float*)d_out);
}